// Round 13
// baseline (860.165 us; speedup 1.0000x reference)
//
#include <hip/hip_runtime.h>
#include <stdint.h>

typedef unsigned short u16;
typedef unsigned int u32;
typedef __attribute__((ext_vector_type(8))) __bf16 bf16x8;
typedef __attribute__((ext_vector_type(4))) float f32x4;
typedef __attribute__((ext_vector_type(4))) u32 u32x4;
typedef __attribute__((ext_vector_type(2))) u32 u32x2;
typedef __attribute__((ext_vector_type(4))) int i32x4;

#define DEV __device__ __forceinline__

constexpr int V = 5000, D = 300, H = 256, BB = 16, T = 512;
constexpr int M = BB * T;      // 8192
constexpr int DP = 320;        // D padded
constexpr int KP = 5024;       // V padded (E k-dim)
constexpr int G4 = 1024;       // 4H
constexpr int NPAD = 5120;     // V padded (out n-dim)

// workspace layout (bytes). ~28 MB.
constexpr size_t OFF_EB    = 0;                                   // bf16 [DP][KP]
constexpr size_t OFF_WXB   = OFF_EB    + (size_t)DP * KP * 2;     // bf16 [G4][DP]
constexpr size_t OFF_UHB   = OFF_WXB   + (size_t)G4 * DP * 2;     // i8 qU [G4][H] + f32 zsc[G4]
constexpr size_t OFF_WOUTB = OFF_UHB   + (size_t)G4 * H * 2;      // bf16 [NPAD][H]
constexpr size_t OFF_GATES = OFF_WOUTB + (size_t)NPAD * H * 2;    // bf16 [T][B][256][4]
constexpr size_t OFF_GALL  = OFF_GATES + (size_t)T * BB * G4 * 2; // bf16 [M][H]

DEV u16 f2bf(float f) {
  u32 i = __builtin_bit_cast(u32, f);
  return (u16)((i + 0x7FFFu + ((i >> 16) & 1u)) >> 16);
}
DEV float bf2f(u16 u) { return __builtin_bit_cast(float, (u32)u << 16); }
DEV f32x4 MFMA(u32x4 a, u32x4 b, f32x4 c) {
  return __builtin_amdgcn_mfma_f32_16x16x32_bf16(
      __builtin_bit_cast(bf16x8, a), __builtin_bit_cast(bf16x8, b), c, 0, 0, 0);
}
DEV i32x4 MFMA8(u32x4 a, u32x4 b, i32x4 c) {
  return __builtin_amdgcn_mfma_i32_16x16x64_i8(
      __builtin_bit_cast(i32x4, a), __builtin_bit_cast(i32x4, b), c, 0, 0, 0);
}
DEV float sigm(float x) { return 1.f / (1.f + __expf(-x)); }
DEV float tanh_s(float x) { float e = __expf(2.f * x); return 1.f - 2.f / (e + 1.f); }

DEV void bar_lds() {
  asm volatile("s_waitcnt lgkmcnt(0)" ::: "memory");
  __builtin_amdgcn_sched_barrier(0);
  __builtin_amdgcn_s_barrier();
  __builtin_amdgcn_sched_barrier(0);
}

// ---------------- K0: weight prep. blocks 0..1023: bf16 conversions; 1024..1279: Uh->i8
__global__ __launch_bounds__(256) void k_prep(
    const float* __restrict__ E, const float* __restrict__ Wf, const float* __restrict__ Wg,
    const float* __restrict__ Wi, const float* __restrict__ Wo,
    const float* __restrict__ Uf, const float* __restrict__ Ug,
    const float* __restrict__ Ui, const float* __restrict__ Uo,
    const float* __restrict__ Wout, char* __restrict__ ws) {
  if (blockIdx.x >= 1024) {  // Uh -> int8 (per-row scale), one wave per row
    char* qU = ws + OFF_UHB;
    float* zsc = (float*)(ws + OFF_UHB + (size_t)G4 * H);
    const int row = (blockIdx.x - 1024) * 4 + (threadIdx.x >> 6);
    const int lane = threadIdx.x & 63;
    const float* Up = (row < 256) ? Uf : (row < 512) ? Ug : (row < 768) ? Ui : Uo;
    f32x4 v = *(const f32x4*)(Up + (size_t)(row & 255) * H + lane * 4);
    float m = fmaxf(fmaxf(fabsf(v[0]), fabsf(v[1])), fmaxf(fabsf(v[2]), fabsf(v[3])));
    for (int i = 1; i < 64; i <<= 1) m = fmaxf(m, __shfl_xor(m, i));
    float inv = (m > 0.f) ? 127.f / m : 0.f;
    int q0 = (int)rintf(v[0] * inv), q1 = (int)rintf(v[1] * inv);
    int q2 = (int)rintf(v[2] * inv), q3 = (int)rintf(v[3] * inv);
    q0 = max(-127, min(127, q0)); q1 = max(-127, min(127, q1));
    q2 = max(-127, min(127, q2)); q3 = max(-127, min(127, q3));
    u32 pk = (u32)(q0 & 255) | ((u32)(q1 & 255) << 8) | ((u32)(q2 & 255) << 16) |
             ((u32)(q3 & 255) << 24);
    *(u32*)(qU + (size_t)row * H + lane * 4) = pk;
    if (lane == 0) zsc[row] = m / 16129.f;  // s_n / 127^2
    return;
  }
  u16* Eb = (u16*)(ws + OFF_EB);
  u16* Wxb = (u16*)(ws + OFF_WXB);
  u16* Wob = (u16*)(ws + OFF_WOUTB);
  const int NE = DP * KP, NW = G4 * DP, NWO = NPAD * H;
  const int total = NE + NW + NWO;
  for (int i = blockIdx.x * blockDim.x + threadIdx.x; i < total; i += 1024 * blockDim.x) {
    int j = i;
    if (j < NE) {
      int nn = j / KP, k = j % KP;
      Eb[j] = f2bf((nn < D && k < V) ? E[(size_t)nn * V + k] : 0.f);
      continue;
    }
    j -= NE;
    if (j < NW) {
      int r = j / DP, k = j % DP;
      const float* Wp = (r < 256) ? Wf : (r < 512) ? Wg : (r < 768) ? Wi : Wo;
      Wxb[j] = f2bf((k < D) ? Wp[(size_t)(r & 255) * D + k] : 0.f);
      continue;
    }
    j -= NW;
    if (j < NWO) {
      int nn = j / H, k = j % H;
      Wob[j] = f2bf((nn < V) ? Wout[(size_t)nn * H + k] : 0.f);
      continue;
    }
  }
}

// ---------------- K1: fused emb+gates, BK=64 (R12 version, unchanged).
__global__ __launch_bounds__(512) void k_embgates(const float* __restrict__ x,
                                                  char* __restrict__ ws) {
  __shared__ __align__(16) char sm[50688];  // As[32*72]@0 (4608B) | Bs[320*72]@4608 (46080B)
  u16* As = (u16*)sm;                        // overlaid by embS[32*328] after staging dead
  u16* Bs = (u16*)(sm + 4608);
  u16* embS = (u16*)sm;
  const u16* Eb = (const u16*)(ws + OFF_EB);
  const u16* Wxb = (const u16*)(ws + OFF_WXB);
  u16* gates = (u16*)(ws + OFF_GATES);

  const int tid = threadIdx.x;
  const int lane = tid & 63, wv = tid >> 6;
  const int l15 = lane & 15, lc = lane >> 4;
  const int it = blockIdx.x;
  const int tc = it >> 4, b = it & 15;
  const int m0x = b * T + tc * 32;

  f32x4 acc[5];
#pragma unroll
  for (int j = 0; j < 5; j++) acc[j] = (f32x4){0.f, 0.f, 0.f, 0.f};
  const int ar = tid >> 4, ak = (tid & 15) * 4;  // x staging: 32 rows x 16 thr x 4 f32
  f32x4 xv0, xv1;
  u32x4 ev0[5], ev1[5];

// K-tail note: Eb reads at k>=KP spill into the adjacent allocated Wxb region; the
// corresponding As entries are 0 (x masked at V), so the MFMA contribution is exactly 0.
#define WEMB_ISSUE(SFX, KS)                                                       \
  do {                                                                            \
    int k0_ = (KS) * 64;                                                          \
    {                                                                             \
      size_t base_ = (size_t)(m0x + ar) * V + k0_ + ak;                           \
      if (k0_ + ak + 3 < V) {                                                     \
        xv##SFX = *(const f32x4*)(x + base_);                                     \
      } else {                                                                    \
        f32x4 t_;                                                                 \
        t_[0] = (k0_ + ak + 0 < V) ? x[base_ + 0] : 0.f;                          \
        t_[1] = (k0_ + ak + 1 < V) ? x[base_ + 1] : 0.f;                          \
        t_[2] = (k0_ + ak + 2 < V) ? x[base_ + 2] : 0.f;                          \
        t_[3] = (k0_ + ak + 3 < V) ? x[base_ + 3] : 0.f;                          \
        xv##SFX = t_;                                                             \
      }                                                                           \
    }                                                                             \
    _Pragma("unroll") for (int p_ = 0; p_ < 5; p_++) {                            \
      int cc_ = tid + 512 * p_;                                                   \
      int n_ = cc_ >> 3, ko_ = (cc_ & 7) * 8;                                     \
      ev##SFX[p_] = *(const u32x4*)(Eb + (size_t)n_ * KP + k0_ + ko_);            \
    }                                                                             \
  } while (0)

#define WEMB_WRITE(SFX)                                                           \
  do {                                                                            \
    {                                                                             \
      union { u16 u[4]; u32x2 v; } ua_;                                           \
      ua_.u[0] = f2bf(xv##SFX[0]); ua_.u[1] = f2bf(xv##SFX[1]);                   \
      ua_.u[2] = f2bf(xv##SFX[2]); ua_.u[3] = f2bf(xv##SFX[3]);                   \
      *(u32x2*)&As[ar * 72 + ak] = ua_.v;                                         \
    }                                                                             \
    _Pragma("unroll") for (int p_ = 0; p_ < 5; p_++) {                            \
      int cc_ = tid + 512 * p_;                                                   \
      int n_ = cc_ >> 3, ko_ = (cc_ & 7) * 8;                                     \
      *(u32x4*)&Bs[n_ * 72 + ko_] = ev##SFX[p_];                                  \
    }                                                                             \
  } while (0)

  const int mt = wv & 1, ntb = (wv >> 1) * 5;
  auto wemb_compute = [&]() {
#pragma unroll
    for (int ksub = 0; ksub < 2; ksub++) {
      u32x4 a = *(const u32x4*)&As[(mt * 16 + l15) * 72 + ksub * 32 + lc * 8];
#pragma unroll
      for (int j = 0; j < 5; j++) {
        u32x4 bb = *(const u32x4*)&Bs[((ntb + j) * 16 + l15) * 72 + ksub * 32 + lc * 8];
        acc[j] = MFMA(a, bb, acc[j]);
      }
    }
  };

  constexpr int NK = 79;  // ceil(5024/64)
  WEMB_ISSUE(0, 0);
  WEMB_ISSUE(1, 1);
  for (int ks = 0; ks < NK; ks += 2) {
    __syncthreads();
    WEMB_WRITE(0);
    if (ks + 2 < NK) WEMB_ISSUE(0, ks + 2);
    __syncthreads();
    wemb_compute();
    if (ks + 1 < NK) {
      __syncthreads();
      WEMB_WRITE(1);
      if (ks + 3 < NK) WEMB_ISSUE(1, ks + 3);
      __syncthreads();
      wemb_compute();
    }
  }
#undef WEMB_ISSUE
#undef WEMB_WRITE
  __syncthreads();  // As/Bs dead; embS overlays
#pragma unroll
  for (int j = 0; j < 5; j++) {
    int nn = (ntb + j) * 16 + l15;
#pragma unroll
    for (int r = 0; r < 4; r++)
      embS[(mt * 16 + lc * 4 + r) * 328 + nn] = f2bf(acc[j][r]);
  }
  __syncthreads();

  // gates: 32m x 1024n, K=DP from embS; B direct from Wxb (L2-hot)
  const int amt = wv & 1, ngrp = wv >> 1;
  f32x4 gacc[16];
#pragma unroll
  for (int j = 0; j < 16; j++) gacc[j] = (f32x4){0.f, 0.f, 0.f, 0.f};
#pragma unroll 1
  for (int kc = 0; kc < 10; kc++) {
    u32x4 a = *(const u32x4*)&embS[(amt * 16 + l15) * 328 + kc * 32 + lc * 8];
#pragma unroll
    for (int nt = 0; nt < 16; nt++) {
      int col = ngrp * 256 + nt * 16 + l15;
      u32x4 bb = *(const u32x4*)(Wxb + (size_t)col * DP + kc * 32 + lc * 8);
      gacc[nt] = MFMA(a, bb, gacc[nt]);
    }
  }
#pragma unroll
  for (int nt = 0; nt < 16; nt++) {
#pragma unroll
    for (int r = 0; r < 4; r++) {
      int t = tc * 32 + amt * 16 + lc * 4 + r;
      int col = ngrp * 256 + nt * 16 + l15;
      int q = col >> 8, nn = col & 255;
      gates[(((size_t)t * 16 + b) * 256 + nn) * 4 + q] = f2bf(gacc[nt][r]);
    }
  }
}

// ---------------- K2: recurrent scan (R10/R11/R12 dieted version, unchanged).
__global__ __launch_bounds__(512) void k_scan(const float* __restrict__ hidden,
                                              const float* __restrict__ ctx,
                                              char* __restrict__ ws) {
  const char* qU = (const char*)(ws + OFF_UHB);
  const float* zsc = (const float*)(ws + OFF_UHB + (size_t)G4 * H);
  const u16* gates = (const u16*)(ws + OFF_GATES);
  u16* gall = (u16*)(ws + OFF_GALL);

  __shared__ __align__(16) char pq[2][2][256];      // [par][b][n] int8 h
  __shared__ __align__(16) int zw[2][8][8][2][16];  // [par][wv][gg*2+j][b][r16] raw i32 z

  const int tid = threadIdx.x;
  const int lane = tid & 63, wv = tid >> 6;
  const int l15 = lane & 15, lc = lane >> 4;

  u32x4 uq[4][2][4];
#pragma unroll
  for (int gg = 0; gg < 4; gg++)
#pragma unroll
    for (int j = 0; j < 2; j++)
#pragma unroll
      for (int kt = 0; kt < 4; kt++)
        uq[gg][j][kt] = *(const u32x4*)(
            qU + (size_t)(gg * 256 + wv * 32 + j * 16 + l15) * H + kt * 64 + lc * 16);

  const int b = lane >> 5, np = lane & 31;
  const int n = wv * 32 + np;
  const int jj = (np >> 4) & 1, rr = np & 15;
  const int b_glob = blockIdx.x * 2 + b;
  float c = ctx[n];
  const float zs0 = zsc[n], zs1 = zsc[n + 256], zs2 = zsc[n + 512], zs3 = zsc[n + 768];
  u32x2 gxc = *(const u32x2*)(gates + (((size_t)0 * 16 + b_glob) * 256 + n) * 4);
  u32x2 gxn = *(const u32x2*)(gates + (((size_t)1 * 16 + b_glob) * 256 + n) * 4);
  const u16* gxp = gates + (((size_t)2 * 16 + b_glob) * 256 + n) * 4;  // prefetch ptr (t+2)
  u16* gallp = gall + (size_t)b_glob * T * H + n;

  {  // h(0): scale 4/127
    const int b0 = tid >> 8, n0i = tid & 255;
    float h0 = hidden[n0i];
    h0 = fminf(3.999f, fmaxf(-3.999f, h0));
    pq[0][b0][n0i] = (char)(int)rintf(h0 * 31.75f);
  }
  __syncthreads();

  // One step; PAR is a compile-time literal so all pq/zw LDS offsets fold to immediates.
  // Prefetch reads past t=T-1 land in the adjacent gall region (allocated, never consumed).
#define SCAN_STEP(PAR, S0, S1, S2, S3)                                                     \
  {                                                                                        \
    u32x4 bfr[4];                                                                          \
    _Pragma("unroll") for (int kt = 0; kt < 4; kt++)                                       \
        bfr[kt] = *(const u32x4*)&pq[PAR][l15 & 1][kt * 64 + lc * 16];                     \
    i32x4 acc[4][2];                                                                       \
    _Pragma("unroll") for (int gg = 0; gg < 4; gg++)                                       \
        _Pragma("unroll") for (int j = 0; j < 2; j++) {                                    \
      i32x4 a = {0, 0, 0, 0};                                                              \
      _Pragma("unroll") for (int kt = 0; kt < 4; kt++)                                     \
          a = MFMA8(uq[gg][j][kt], bfr[kt], a);                                            \
      acc[gg][j] = a;                                                                      \
    }                                                                                      \
    if (l15 < 2) {                                                                         \
      _Pragma("unroll") for (int gg = 0; gg < 4; gg++)                                     \
          _Pragma("unroll") for (int j = 0; j < 2; j++)                                    \
              *(i32x4*)&zw[PAR][wv][gg * 2 + j][l15][lc * 4] = acc[gg][j];                 \
    }                                                                                      \
    asm volatile("s_waitcnt lgkmcnt(0)" ::: "memory");                                     \
    __builtin_amdgcn_sched_barrier(0);                                                     \
    float z0 = (float)zw[PAR][wv][0 + jj][b][rr] * (S0) + bf2f((u16)(gxc[0] & 0xFFFFu));   \
    float z1 = (float)zw[PAR][wv][2 + jj][b][rr] * (S1) + bf2f((u16)(gxc[0] >> 16));       \
    float z2 = (float)zw[PAR][wv][4 + jj][b][rr] * (S2) + bf2f((u16)(gxc[1] & 0xFFFFu));   \
    float z3 = (float)zw[PAR][wv][6 + jj][b][rr] * (S3) + bf2f((u16)(gxc[1] >> 16));       \
    float fv = sigm(z0), gv = tanh_s(z1), iv = sigm(z2), ov = sigm(z3);                    \
    c = gv * iv + c * fv;                                                                  \
    float hn = ov * tanh_s(c);                                                             \
    *gallp = f2bf(gv);                                                                     \
    gallp += H;                                                                            \
    pq[(PAR) ^ 1][b][n] = (char)(int)rintf(hn * 127.f);                                    \
    gxc = gxn;                                                                             \
    gxn = *(const u32x2*)gxp;                                                              \
    gxp += 16384; /* 16*256*4 u16 per t */                                                 \
    bar_lds();                                                                             \
  }

  SCAN_STEP(0, zs0 * 4.f, zs1 * 4.f, zs2 * 4.f, zs3 * 4.f)  // t=0 (h0 scale folded)
#pragma unroll 1
  for (int t = 1; t + 1 < T; t += 2) {
    SCAN_STEP(1, zs0, zs1, zs2, zs3)
    SCAN_STEP(0, zs0, zs1, zs2, zs3)
  }
  SCAN_STEP(1, zs0, zs1, zs2, zs3)  // t = T-1
#undef SCAN_STEP
}

// ---------------- K3: out = g_all @ Wout^T (BM=64, BN=256, K=H), barrier-free GEMM:
// A/B fragments loaded directly from L2-resident gall (4MB, 20x reuse) and Wob (2.6MB,
// 128x reuse) at the per-lane addresses the old LDS reads used -> bit-identical math,
// zero main-loop barriers. Epilogue: LDS transpose + coalesced f32x4 stores (unchanged).
__global__ __launch_bounds__(256) void k_out(char* __restrict__ ws, float* __restrict__ out) {
  const u16* gall = (const u16*)(ws + OFF_GALL);
  const u16* Wob = (const u16*)(ws + OFF_WOUTB);
  __shared__ __align__(16) float tb[64 * 132];

  const int tid = threadIdx.x;
  const int blk = blockIdx.x;
  const int m0 = (blk / 20) * 64, n0 = (blk % 20) * 256;
  const int lane = tid & 63, wv = tid >> 6;
  const int l15 = lane & 15, lc = lane >> 4;

  f32x4 acc[16];
#pragma unroll
  for (int j = 0; j < 16; j++) acc[j] = (f32x4){0.f, 0.f, 0.f, 0.f};

  // A fragments: row m0+wv*16+l15, k = ks*32 + lc*8 (8 k-steps, K=H=256)
  u32x4 afr[8];
  const u16* ga = gall + (size_t)(m0 + wv * 16 + l15) * H + lc * 8;
#pragma unroll
  for (int ks = 0; ks < 8; ks++) afr[ks] = *(const u32x4*)(ga + ks * 32);

#pragma unroll
  for (int nt = 0; nt < 16; nt++) {
    const u16* wb = Wob + (size_t)(n0 + nt * 16 + l15) * H + lc * 8;
#pragma unroll
    for (int ks = 0; ks < 8; ks++) {
      u32x4 bfr = *(const u32x4*)(wb + ks * 32);
      acc[nt] = MFMA(afr[ks], bfr, acc[nt]);
    }
  }

  // epilogue: LDS transpose in two 64x128 halves -> coalesced dwordx4 stores
#pragma unroll
  for (int h = 0; h < 2; h++) {
    __syncthreads();
#pragma unroll
    for (int nt = 0; nt < 8; nt++) {
#pragma unroll
      for (int r = 0; r < 4; r++)
        tb[(wv * 16 + lc * 4 + r) * 132 + nt * 16 + l15] = acc[h * 8 + nt][r];
    }
    __syncthreads();
#pragma unroll
    for (int cc = 0; cc < 8; cc++) {
      int idx = cc * 256 + tid;
      int row = idx >> 5, c4 = (idx & 31) * 4;
      int gcol = n0 + h * 128 + c4;
      if (gcol + 3 < V) {
        f32x4 v = *(const f32x4*)&tb[row * 132 + c4];
        *(f32x4*)&out[(size_t)(m0 + row) * V + gcol] = v;
      }
    }
  }
}

extern "C" void kernel_launch(void* const* d_in, const int* in_sizes, int n_in,
                              void* d_out, int out_size, void* d_ws, size_t ws_size,
                              hipStream_t stream) {
  (void)in_sizes; (void)n_in; (void)out_size; (void)ws_size;  // needs ~28 MB of ws
  const float* x      = (const float*)d_in[0];
  const float* hidden = (const float*)d_in[1];
  const float* ctx    = (const float*)d_in[2];
  const float* E      = (const float*)d_in[3];
  const float* Wf     = (const float*)d_in[4];
  const float* Uf     = (const float*)d_in[5];
  const float* Wg     = (const float*)d_in[6];
  const float* Ug     = (const float*)d_in[7];
  const float* Wi     = (const float*)d_in[8];
  const float* Ui     = (const float*)d_in[9];
  const float* Wo     = (const float*)d_in[10];
  const float* Uo     = (const float*)d_in[11];
  const float* Wout   = (const float*)d_in[12];
  char* ws = (char*)d_ws;
  float* out = (float*)d_out;

  hipLaunchKernelGGL(k_prep, dim3(1280), dim3(256), 0, stream,
                     E, Wf, Wg, Wi, Wo, Uf, Ug, Ui, Uo, Wout, ws);
  hipLaunchKernelGGL(k_embgates, dim3(256), dim3(512), 0, stream, x, ws);
  hipLaunchKernelGGL(k_scan, dim3(8), dim3(512), 0, stream, hidden, ctx, ws);
  hipLaunchKernelGGL(k_out, dim3((M / 64) * 20), dim3(256), 0, stream, ws, out);
}

// Round 14
// 725.981 us; speedup vs baseline: 1.1848x; 1.1848x over previous
//
#include <hip/hip_runtime.h>
#include <stdint.h>

typedef unsigned short u16;
typedef unsigned int u32;
typedef __attribute__((ext_vector_type(8))) __bf16 bf16x8;
typedef __attribute__((ext_vector_type(4))) float f32x4;
typedef __attribute__((ext_vector_type(4))) u32 u32x4;
typedef __attribute__((ext_vector_type(2))) u32 u32x2;
typedef __attribute__((ext_vector_type(4))) int i32x4;

#define DEV __device__ __forceinline__

constexpr int V = 5000, D = 300, H = 256, BB = 16, T = 512;
constexpr int M = BB * T;      // 8192
constexpr int DP = 320;        // D padded
constexpr int KP = 5024;       // V padded (E k-dim)
constexpr int G4 = 1024;       // 4H
constexpr int NPAD = 5120;     // V padded (out n-dim)

// workspace layout (bytes). ~28 MB.
constexpr size_t OFF_EB    = 0;                                   // bf16 [DP][KP]
constexpr size_t OFF_WXB   = OFF_EB    + (size_t)DP * KP * 2;     // bf16 [G4][DP]
constexpr size_t OFF_UHB   = OFF_WXB   + (size_t)G4 * DP * 2;     // i8 qU [G4][H] + f32 zsc[G4]
constexpr size_t OFF_WOUTB = OFF_UHB   + (size_t)G4 * H * 2;      // bf16 [NPAD][H]
constexpr size_t OFF_GATES = OFF_WOUTB + (size_t)NPAD * H * 2;    // bf16 [T][B][256][4]
constexpr size_t OFF_GALL  = OFF_GATES + (size_t)T * BB * G4 * 2; // bf16 [M][H]

DEV u16 f2bf(float f) {
  u32 i = __builtin_bit_cast(u32, f);
  return (u16)((i + 0x7FFFu + ((i >> 16) & 1u)) >> 16);
}
DEV float bf2f(u16 u) { return __builtin_bit_cast(float, (u32)u << 16); }
DEV f32x4 MFMA(u32x4 a, u32x4 b, f32x4 c) {
  return __builtin_amdgcn_mfma_f32_16x16x32_bf16(
      __builtin_bit_cast(bf16x8, a), __builtin_bit_cast(bf16x8, b), c, 0, 0, 0);
}
DEV i32x4 MFMA8(u32x4 a, u32x4 b, i32x4 c) {
  return __builtin_amdgcn_mfma_i32_16x16x64_i8(
      __builtin_bit_cast(i32x4, a), __builtin_bit_cast(i32x4, b), c, 0, 0, 0);
}
DEV float sigm(float x) { return 1.f / (1.f + __expf(-x)); }
DEV float tanh_s(float x) { float e = __expf(2.f * x); return 1.f - 2.f / (e + 1.f); }

DEV void bar_lds() {
  asm volatile("s_waitcnt lgkmcnt(0)" ::: "memory");
  __builtin_amdgcn_sched_barrier(0);
  __builtin_amdgcn_s_barrier();
  __builtin_amdgcn_sched_barrier(0);
}

// ---------------- K0: weight prep. blocks 0..1023: bf16 conversions; 1024..1279: Uh->i8
__global__ __launch_bounds__(256) void k_prep(
    const float* __restrict__ E, const float* __restrict__ Wf, const float* __restrict__ Wg,
    const float* __restrict__ Wi, const float* __restrict__ Wo,
    const float* __restrict__ Uf, const float* __restrict__ Ug,
    const float* __restrict__ Ui, const float* __restrict__ Uo,
    const float* __restrict__ Wout, char* __restrict__ ws) {
  if (blockIdx.x >= 1024) {  // Uh -> int8 (per-row scale), one wave per row
    char* qU = ws + OFF_UHB;
    float* zsc = (float*)(ws + OFF_UHB + (size_t)G4 * H);
    const int row = (blockIdx.x - 1024) * 4 + (threadIdx.x >> 6);
    const int lane = threadIdx.x & 63;
    const float* Up = (row < 256) ? Uf : (row < 512) ? Ug : (row < 768) ? Ui : Uo;
    f32x4 v = *(const f32x4*)(Up + (size_t)(row & 255) * H + lane * 4);
    float m = fmaxf(fmaxf(fabsf(v[0]), fabsf(v[1])), fmaxf(fabsf(v[2]), fabsf(v[3])));
    for (int i = 1; i < 64; i <<= 1) m = fmaxf(m, __shfl_xor(m, i));
    float inv = (m > 0.f) ? 127.f / m : 0.f;
    int q0 = (int)rintf(v[0] * inv), q1 = (int)rintf(v[1] * inv);
    int q2 = (int)rintf(v[2] * inv), q3 = (int)rintf(v[3] * inv);
    q0 = max(-127, min(127, q0)); q1 = max(-127, min(127, q1));
    q2 = max(-127, min(127, q2)); q3 = max(-127, min(127, q3));
    u32 pk = (u32)(q0 & 255) | ((u32)(q1 & 255) << 8) | ((u32)(q2 & 255) << 16) |
             ((u32)(q3 & 255) << 24);
    *(u32*)(qU + (size_t)row * H + lane * 4) = pk;
    if (lane == 0) zsc[row] = m / 16129.f;  // s_n / 127^2
    return;
  }
  u16* Eb = (u16*)(ws + OFF_EB);
  u16* Wxb = (u16*)(ws + OFF_WXB);
  u16* Wob = (u16*)(ws + OFF_WOUTB);
  const int NE = DP * KP, NW = G4 * DP, NWO = NPAD * H;
  const int total = NE + NW + NWO;
  for (int i = blockIdx.x * blockDim.x + threadIdx.x; i < total; i += 1024 * blockDim.x) {
    int j = i;
    if (j < NE) {
      int nn = j / KP, k = j % KP;
      Eb[j] = f2bf((nn < D && k < V) ? E[(size_t)nn * V + k] : 0.f);
      continue;
    }
    j -= NE;
    if (j < NW) {
      int r = j / DP, k = j % DP;
      const float* Wp = (r < 256) ? Wf : (r < 512) ? Wg : (r < 768) ? Wi : Wo;
      Wxb[j] = f2bf((k < D) ? Wp[(size_t)(r & 255) * D + k] : 0.f);
      continue;
    }
    j -= NW;
    if (j < NWO) {
      int nn = j / H, k = j % H;
      Wob[j] = f2bf((nn < V) ? Wout[(size_t)nn * H + k] : 0.f);
      continue;
    }
  }
}

// ---------------- K1: fused emb+gates, BK=64 (R12 version, unchanged).
__global__ __launch_bounds__(512) void k_embgates(const float* __restrict__ x,
                                                  char* __restrict__ ws) {
  __shared__ __align__(16) char sm[50688];  // As[32*72]@0 (4608B) | Bs[320*72]@4608 (46080B)
  u16* As = (u16*)sm;                        // overlaid by embS[32*328] after staging dead
  u16* Bs = (u16*)(sm + 4608);
  u16* embS = (u16*)sm;
  const u16* Eb = (const u16*)(ws + OFF_EB);
  const u16* Wxb = (const u16*)(ws + OFF_WXB);
  u16* gates = (u16*)(ws + OFF_GATES);

  const int tid = threadIdx.x;
  const int lane = tid & 63, wv = tid >> 6;
  const int l15 = lane & 15, lc = lane >> 4;
  const int it = blockIdx.x;
  const int tc = it >> 4, b = it & 15;
  const int m0x = b * T + tc * 32;

  f32x4 acc[5];
#pragma unroll
  for (int j = 0; j < 5; j++) acc[j] = (f32x4){0.f, 0.f, 0.f, 0.f};
  const int ar = tid >> 4, ak = (tid & 15) * 4;  // x staging: 32 rows x 16 thr x 4 f32
  f32x4 xv0, xv1;
  u32x4 ev0[5], ev1[5];

// K-tail note: Eb reads at k>=KP spill into the adjacent allocated Wxb region; the
// corresponding As entries are 0 (x masked at V), so the MFMA contribution is exactly 0.
#define WEMB_ISSUE(SFX, KS)                                                       \
  do {                                                                            \
    int k0_ = (KS) * 64;                                                          \
    {                                                                             \
      size_t base_ = (size_t)(m0x + ar) * V + k0_ + ak;                           \
      if (k0_ + ak + 3 < V) {                                                     \
        xv##SFX = *(const f32x4*)(x + base_);                                     \
      } else {                                                                    \
        f32x4 t_;                                                                 \
        t_[0] = (k0_ + ak + 0 < V) ? x[base_ + 0] : 0.f;                          \
        t_[1] = (k0_ + ak + 1 < V) ? x[base_ + 1] : 0.f;                          \
        t_[2] = (k0_ + ak + 2 < V) ? x[base_ + 2] : 0.f;                          \
        t_[3] = (k0_ + ak + 3 < V) ? x[base_ + 3] : 0.f;                          \
        xv##SFX = t_;                                                             \
      }                                                                           \
    }                                                                             \
    _Pragma("unroll") for (int p_ = 0; p_ < 5; p_++) {                            \
      int cc_ = tid + 512 * p_;                                                   \
      int n_ = cc_ >> 3, ko_ = (cc_ & 7) * 8;                                     \
      ev##SFX[p_] = *(const u32x4*)(Eb + (size_t)n_ * KP + k0_ + ko_);            \
    }                                                                             \
  } while (0)

#define WEMB_WRITE(SFX)                                                           \
  do {                                                                            \
    {                                                                             \
      union { u16 u[4]; u32x2 v; } ua_;                                           \
      ua_.u[0] = f2bf(xv##SFX[0]); ua_.u[1] = f2bf(xv##SFX[1]);                   \
      ua_.u[2] = f2bf(xv##SFX[2]); ua_.u[3] = f2bf(xv##SFX[3]);                   \
      *(u32x2*)&As[ar * 72 + ak] = ua_.v;                                         \
    }                                                                             \
    _Pragma("unroll") for (int p_ = 0; p_ < 5; p_++) {                            \
      int cc_ = tid + 512 * p_;                                                   \
      int n_ = cc_ >> 3, ko_ = (cc_ & 7) * 8;                                     \
      *(u32x4*)&Bs[n_ * 72 + ko_] = ev##SFX[p_];                                  \
    }                                                                             \
  } while (0)

  const int mt = wv & 1, ntb = (wv >> 1) * 5;
  auto wemb_compute = [&]() {
#pragma unroll
    for (int ksub = 0; ksub < 2; ksub++) {
      u32x4 a = *(const u32x4*)&As[(mt * 16 + l15) * 72 + ksub * 32 + lc * 8];
#pragma unroll
      for (int j = 0; j < 5; j++) {
        u32x4 bb = *(const u32x4*)&Bs[((ntb + j) * 16 + l15) * 72 + ksub * 32 + lc * 8];
        acc[j] = MFMA(a, bb, acc[j]);
      }
    }
  };

  constexpr int NK = 79;  // ceil(5024/64)
  WEMB_ISSUE(0, 0);
  WEMB_ISSUE(1, 1);
  for (int ks = 0; ks < NK; ks += 2) {
    __syncthreads();
    WEMB_WRITE(0);
    if (ks + 2 < NK) WEMB_ISSUE(0, ks + 2);
    __syncthreads();
    wemb_compute();
    if (ks + 1 < NK) {
      __syncthreads();
      WEMB_WRITE(1);
      if (ks + 3 < NK) WEMB_ISSUE(1, ks + 3);
      __syncthreads();
      wemb_compute();
    }
  }
#undef WEMB_ISSUE
#undef WEMB_WRITE
  __syncthreads();  // As/Bs dead; embS overlays
#pragma unroll
  for (int j = 0; j < 5; j++) {
    int nn = (ntb + j) * 16 + l15;
#pragma unroll
    for (int r = 0; r < 4; r++)
      embS[(mt * 16 + lc * 4 + r) * 328 + nn] = f2bf(acc[j][r]);
  }
  __syncthreads();

  // gates: 32m x 1024n, K=DP from embS; B direct from Wxb (L2-hot)
  const int amt = wv & 1, ngrp = wv >> 1;
  f32x4 gacc[16];
#pragma unroll
  for (int j = 0; j < 16; j++) gacc[j] = (f32x4){0.f, 0.f, 0.f, 0.f};
#pragma unroll 1
  for (int kc = 0; kc < 10; kc++) {
    u32x4 a = *(const u32x4*)&embS[(amt * 16 + l15) * 328 + kc * 32 + lc * 8];
#pragma unroll
    for (int nt = 0; nt < 16; nt++) {
      int col = ngrp * 256 + nt * 16 + l15;
      u32x4 bb = *(const u32x4*)(Wxb + (size_t)col * DP + kc * 32 + lc * 8);
      gacc[nt] = MFMA(a, bb, gacc[nt]);
    }
  }
#pragma unroll
  for (int nt = 0; nt < 16; nt++) {
#pragma unroll
    for (int r = 0; r < 4; r++) {
      int t = tc * 32 + amt * 16 + lc * 4 + r;
      int col = ngrp * 256 + nt * 16 + l15;
      int q = col >> 8, nn = col & 255;
      gates[(((size_t)t * 16 + b) * 256 + nn) * 4 + q] = f2bf(gacc[nt][r]);
    }
  }
}

// ---------------- K2: recurrent scan (R10/R11/R12 dieted version, unchanged).
__global__ __launch_bounds__(512) void k_scan(const float* __restrict__ hidden,
                                              const float* __restrict__ ctx,
                                              char* __restrict__ ws) {
  const char* qU = (const char*)(ws + OFF_UHB);
  const float* zsc = (const float*)(ws + OFF_UHB + (size_t)G4 * H);
  const u16* gates = (const u16*)(ws + OFF_GATES);
  u16* gall = (u16*)(ws + OFF_GALL);

  __shared__ __align__(16) char pq[2][2][256];      // [par][b][n] int8 h
  __shared__ __align__(16) int zw[2][8][8][2][16];  // [par][wv][gg*2+j][b][r16] raw i32 z

  const int tid = threadIdx.x;
  const int lane = tid & 63, wv = tid >> 6;
  const int l15 = lane & 15, lc = lane >> 4;

  u32x4 uq[4][2][4];
#pragma unroll
  for (int gg = 0; gg < 4; gg++)
#pragma unroll
    for (int j = 0; j < 2; j++)
#pragma unroll
      for (int kt = 0; kt < 4; kt++)
        uq[gg][j][kt] = *(const u32x4*)(
            qU + (size_t)(gg * 256 + wv * 32 + j * 16 + l15) * H + kt * 64 + lc * 16);

  const int b = lane >> 5, np = lane & 31;
  const int n = wv * 32 + np;
  const int jj = (np >> 4) & 1, rr = np & 15;
  const int b_glob = blockIdx.x * 2 + b;
  float c = ctx[n];
  const float zs0 = zsc[n], zs1 = zsc[n + 256], zs2 = zsc[n + 512], zs3 = zsc[n + 768];
  u32x2 gxc = *(const u32x2*)(gates + (((size_t)0 * 16 + b_glob) * 256 + n) * 4);
  u32x2 gxn = *(const u32x2*)(gates + (((size_t)1 * 16 + b_glob) * 256 + n) * 4);
  const u16* gxp = gates + (((size_t)2 * 16 + b_glob) * 256 + n) * 4;  // prefetch ptr (t+2)
  u16* gallp = gall + (size_t)b_glob * T * H + n;

  {  // h(0): scale 4/127
    const int b0 = tid >> 8, n0i = tid & 255;
    float h0 = hidden[n0i];
    h0 = fminf(3.999f, fmaxf(-3.999f, h0));
    pq[0][b0][n0i] = (char)(int)rintf(h0 * 31.75f);
  }
  __syncthreads();

  // One step; PAR is a compile-time literal so all pq/zw LDS offsets fold to immediates.
  // Prefetch reads past t=T-1 land in the adjacent gall region (allocated, never consumed).
#define SCAN_STEP(PAR, S0, S1, S2, S3)                                                     \
  {                                                                                        \
    u32x4 bfr[4];                                                                          \
    _Pragma("unroll") for (int kt = 0; kt < 4; kt++)                                       \
        bfr[kt] = *(const u32x4*)&pq[PAR][l15 & 1][kt * 64 + lc * 16];                     \
    i32x4 acc[4][2];                                                                       \
    _Pragma("unroll") for (int gg = 0; gg < 4; gg++)                                       \
        _Pragma("unroll") for (int j = 0; j < 2; j++) {                                    \
      i32x4 a = {0, 0, 0, 0};                                                              \
      _Pragma("unroll") for (int kt = 0; kt < 4; kt++)                                     \
          a = MFMA8(uq[gg][j][kt], bfr[kt], a);                                            \
      acc[gg][j] = a;                                                                      \
    }                                                                                      \
    if (l15 < 2) {                                                                         \
      _Pragma("unroll") for (int gg = 0; gg < 4; gg++)                                     \
          _Pragma("unroll") for (int j = 0; j < 2; j++)                                    \
              *(i32x4*)&zw[PAR][wv][gg * 2 + j][l15][lc * 4] = acc[gg][j];                 \
    }                                                                                      \
    asm volatile("s_waitcnt lgkmcnt(0)" ::: "memory");                                     \
    __builtin_amdgcn_sched_barrier(0);                                                     \
    float z0 = (float)zw[PAR][wv][0 + jj][b][rr] * (S0) + bf2f((u16)(gxc[0] & 0xFFFFu));   \
    float z1 = (float)zw[PAR][wv][2 + jj][b][rr] * (S1) + bf2f((u16)(gxc[0] >> 16));       \
    float z2 = (float)zw[PAR][wv][4 + jj][b][rr] * (S2) + bf2f((u16)(gxc[1] & 0xFFFFu));   \
    float z3 = (float)zw[PAR][wv][6 + jj][b][rr] * (S3) + bf2f((u16)(gxc[1] >> 16));       \
    float fv = sigm(z0), gv = tanh_s(z1), iv = sigm(z2), ov = sigm(z3);                    \
    c = gv * iv + c * fv;                                                                  \
    float hn = ov * tanh_s(c);                                                             \
    *gallp = f2bf(gv);                                                                     \
    gallp += H;                                                                            \
    pq[(PAR) ^ 1][b][n] = (char)(int)rintf(hn * 127.f);                                    \
    gxc = gxn;                                                                             \
    gxn = *(const u32x2*)gxp;                                                              \
    gxp += 16384; /* 16*256*4 u16 per t */                                                 \
    bar_lds();                                                                             \
  }

  SCAN_STEP(0, zs0 * 4.f, zs1 * 4.f, zs2 * 4.f, zs3 * 4.f)  // t=0 (h0 scale folded)
#pragma unroll 1
  for (int t = 1; t + 1 < T; t += 2) {
    SCAN_STEP(1, zs0, zs1, zs2, zs3)
    SCAN_STEP(0, zs0, zs1, zs2, zs3)
  }
  SCAN_STEP(1, zs0, zs1, zs2, zs3)  // t = T-1
#undef SCAN_STEP
}

// ---------------- K3: out = g_all @ Wout^T (BM=64, BN=256, K=H) + coalesced f32x4 stores
__global__ __launch_bounds__(256) void k_out(char* __restrict__ ws, float* __restrict__ out) {
  const u16* gall = (const u16*)(ws + OFF_GALL);
  const u16* Wob = (const u16*)(ws + OFF_WOUTB);
  __shared__ __align__(16) u16 As[64 * 40];
  __shared__ __align__(16) u16 Bs[256 * 40];
  __shared__ __align__(16) float tb[64 * 132];

  const int tid = threadIdx.x;
  const int blk = blockIdx.x;
  const int m0 = (blk / 20) * 64, n0 = (blk % 20) * 256;
  const int lane = tid & 63, wv = tid >> 6;
  const int l15 = lane & 15, lc = lane >> 4;

  f32x4 acc[16];
#pragma unroll
  for (int j = 0; j < 16; j++) acc[j] = (f32x4){0.f, 0.f, 0.f, 0.f};

  u32x4 av0, av1;
  u32x4 bv0[4], bv1[4];

#define OUT_ISSUE(SFX, KS)                                                        \
  do {                                                                            \
    int k0_ = (KS) * 32;                                                          \
    {                                                                             \
      int r_ = tid >> 2, ko_ = (tid & 3) * 8;                                     \
      av##SFX = *(const u32x4*)(gall + (size_t)(m0 + r_) * H + k0_ + ko_);        \
    }                                                                             \
    _Pragma("unroll") for (int j_ = 0; j_ < 4; j_++) {                            \
      int c_ = tid + 256 * j_;                                                    \
      int n_ = c_ >> 2, ko_ = (c_ & 3) * 8;                                       \
      bv##SFX[j_] = *(const u32x4*)(Wob + (size_t)(n0 + n_) * H + k0_ + ko_);     \
    }                                                                             \
  } while (0)

#define OUT_WRITE(SFX)                                                            \
  do {                                                                            \
    {                                                                             \
      int r_ = tid >> 2, ko_ = (tid & 3) * 8;                                     \
      *(u32x4*)&As[r_ * 40 + ko_] = av##SFX;                                      \
    }                                                                             \
    _Pragma("unroll") for (int j_ = 0; j_ < 4; j_++) {                            \
      int c_ = tid + 256 * j_;                                                    \
      int n_ = c_ >> 2, ko_ = (c_ & 3) * 8;                                       \
      *(u32x4*)&Bs[n_ * 40 + ko_] = bv##SFX[j_];                                  \
    }                                                                             \
  } while (0)

  auto out_compute = [&]() {
    u32x4 a = *(const u32x4*)&As[(wv * 16 + l15) * 40 + lc * 8];
#pragma unroll
    for (int nt = 0; nt < 16; nt++) {
      u32x4 b = *(const u32x4*)&Bs[(nt * 16 + l15) * 40 + lc * 8];
      acc[nt] = MFMA(a, b, acc[nt]);
    }
  };

  constexpr int NK = 8;  // H/32
  OUT_ISSUE(0, 0);
  OUT_ISSUE(1, 1);
  for (int ks = 0; ks < NK; ks += 2) {
    __syncthreads();
    OUT_WRITE(0);
    if (ks + 2 < NK) OUT_ISSUE(0, ks + 2);
    __syncthreads();
    out_compute();
    __syncthreads();
    OUT_WRITE(1);
    if (ks + 3 < NK) OUT_ISSUE(1, ks + 3);
    __syncthreads();
    out_compute();
  }

  // epilogue: LDS transpose in two 64x128 halves -> coalesced dwordx4 stores
#pragma unroll
  for (int h = 0; h < 2; h++) {
    __syncthreads();
#pragma unroll
    for (int nt = 0; nt < 8; nt++) {
#pragma unroll
      for (int r = 0; r < 4; r++)
        tb[(wv * 16 + lc * 4 + r) * 132 + nt * 16 + l15] = acc[h * 8 + nt][r];
    }
    __syncthreads();
#pragma unroll
    for (int cc = 0; cc < 8; cc++) {
      int idx = cc * 256 + tid;
      int row = idx >> 5, c4 = (idx & 31) * 4;
      int gcol = n0 + h * 128 + c4;
      if (gcol + 3 < V) {
        f32x4 v = *(const f32x4*)&tb[row * 132 + c4];
        *(f32x4*)&out[(size_t)(m0 + row) * V + gcol] = v;
      }
    }
  }
#undef OUT_ISSUE
#undef OUT_WRITE
}

extern "C" void kernel_launch(void* const* d_in, const int* in_sizes, int n_in,
                              void* d_out, int out_size, void* d_ws, size_t ws_size,
                              hipStream_t stream) {
  (void)in_sizes; (void)n_in; (void)out_size; (void)ws_size;  // needs ~28 MB of ws
  const float* x      = (const float*)d_in[0];
  const float* hidden = (const float*)d_in[1];
  const float* ctx    = (const float*)d_in[2];
  const float* E      = (const float*)d_in[3];
  const float* Wf     = (const float*)d_in[4];
  const float* Uf     = (const float*)d_in[5];
  const float* Wg     = (const float*)d_in[6];
  const float* Ug     = (const float*)d_in[7];
  const float* Wi     = (const float*)d_in[8];
  const float* Ui     = (const float*)d_in[9];
  const float* Wo     = (const float*)d_in[10];
  const float* Uo     = (const float*)d_in[11];
  const float* Wout   = (const float*)d_in[12];
  char* ws = (char*)d_ws;
  float* out = (float*)d_out;

  hipLaunchKernelGGL(k_prep, dim3(1280), dim3(256), 0, stream,
                     E, Wf, Wg, Wi, Wo, Uf, Ug, Ui, Uo, Wout, ws);
  hipLaunchKernelGGL(k_embgates, dim3(256), dim3(512), 0, stream, x, ws);
  hipLaunchKernelGGL(k_scan, dim3(8), dim3(512), 0, stream, hidden, ctx, ws);
  hipLaunchKernelGGL(k_out, dim3((M / 64) * 20), dim3(256), 0, stream, ws, out);
}